// Round 3
// baseline (196.695 us; speedup 1.0000x reference)
//
#include <hip/hip_runtime.h>
#include <cstddef>

// Problem geometry (fixed by the reference)
constexpr int BB  = 16;                 // batch
constexpr int JJ  = 15;                 // joints
constexpr int MM  = 10;                 // bboxes
constexpr int CX  = 80, CY = 80, CZ = 20;
constexpr int NB  = CX * CY * CZ;       // 128000 voxels
constexpr int HMW = 240, HMH = 128;     // heatmap w,h

// n = ix*CY*CZ + iy*CZ + iz   (meshgrid 'ij', ravel)
// cube out: [B, J, NB] ; grids out: [B, NB, 3] appended after cubes.

__global__ __launch_bounds__(256) void project_kernel(
    const float* __restrict__ hm,      // [B,J,HMH,HMW]
    const float* __restrict__ gc,      // [B,3]
    const float* __restrict__ center,  // [B,2]
    const float* __restrict__ scale,   // [B]
    const float* __restrict__ Rm,      // [B,3,3]
    const float* __restrict__ Tm,      // [B,3,1]
    const float* __restrict__ fv,      // [B,2]
    const float* __restrict__ cv,      // [B,2]
    const float* __restrict__ kd,      // [B,3]
    const float* __restrict__ pd,      // [B,2]
    const float* __restrict__ bbox,    // [B,M,4]
    const float* __restrict__ dep,     // [B,M]
    const float* __restrict__ dnf,     // [B]
    float* __restrict__ out)           // cubes ++ grids
{
    const int blocksPerB = NB / 256;   // 500
    const int b = blockIdx.x / blocksPerB;
    const int n = (blockIdx.x % blocksPerB) * 256 + threadIdx.x;

    const int iz  = n % CZ;
    const int rem = n / CZ;
    const int iy  = rem % CY;
    const int ixg = rem / CY;

    // grid point (linspace endpoints inclusive)
    const float gx = -4000.0f + (float)ixg * (8000.0f / 79.0f) + gc[b * 3 + 0];
    const float gy = -4000.0f + (float)iy  * (8000.0f / 79.0f) + gc[b * 3 + 1];
    const float gz = -1000.0f + (float)iz  * (2000.0f / 19.0f) + gc[b * 3 + 2];

    // ---- projection: xcam = R p - T ----
    const float* R = Rm + b * 9;
    const float* T = Tm + b * 3;
    const float xc = R[0] * gx + R[1] * gy + R[2] * gz - T[0];
    const float yc = R[3] * gx + R[4] * gy + R[5] * gz - T[1];
    const float zc = R[6] * gx + R[7] * gy + R[8] * gz - T[2];

    const float invz = 1.0f / (zc + 1e-5f);
    const float ynx = xc * invz;
    const float yny = yc * invz;
    const float r2  = ynx * ynx + yny * yny;
    const float k0 = kd[b * 3 + 0], k1 = kd[b * 3 + 1], k2 = kd[b * 3 + 2];
    const float radial = 1.0f + k0 * r2 + k1 * r2 * r2 + k2 * r2 * r2 * r2;
    const float p0 = pd[b * 2 + 0], p1 = pd[b * 2 + 1];
    const float tn = p0 * yny + p1 * ynx;
    const float sm = radial + 2.0f * tn;
    const float ux = ynx * sm + p1 * r2;
    const float uy = yny * sm + p0 * r2;
    float xpix = fv[b * 2 + 0] * ux + cv[b * 2 + 0];
    float ypix = fv[b * 2 + 1] * uy + cv[b * 2 + 1];

    const float c0 = center[b * 2 + 0], c1 = center[b * 2 + 1];
    const float width = c0 * 2.0f, height = c1 * 2.0f;
    const bool bound = (xpix >= 0.0f) && (ypix >= 0.0f) &&
                       (xpix < width) && (ypix < height);
    const float mxwh = fmaxf(width, height);
    xpix = fminf(fmaxf(xpix, -1.0f), mxwh);
    ypix = fminf(fmaxf(ypix, -1.0f), mxwh);

    // ---- crop transform -> image coords -> heatmap coords ----
    const float h = 200.0f * scale[b];
    const float ximg = (960.0f / h) * xpix + 960.0f * (-c0 / h + 0.5f);
    const float yimg = (512.0f / h) * ypix + 512.0f * (-c1 / h + 0.5f);
    const float xhm = ximg * (240.0f / 960.0f);
    const float yhm = yimg * (128.0f / 512.0f);

    // ---- sample grid (normalized, clipped to [-1.1, 1.1]) ----
    const float sgx = fminf(fmaxf(xhm / 239.0f * 2.0f - 1.0f, -1.1f), 1.1f);
    const float sgy = fminf(fmaxf(yhm / 127.0f * 2.0f - 1.0f, -1.1f), 1.1f);
    const float fx = (sgx + 1.0f) * 0.5f * 239.0f;
    const float fy = (sgy + 1.0f) * 0.5f * 127.0f;
    const float fx0 = floorf(fx), fy0 = floorf(fy);
    const float wxf = fx - fx0, wyf = fy - fy0;

    const bool okx0 = (fx0 >= 0.0f) && (fx0 <= 239.0f);
    const bool okx1 = (fx0 + 1.0f >= 0.0f) && (fx0 + 1.0f <= 239.0f);
    const bool oky0 = (fy0 >= 0.0f) && (fy0 <= 127.0f);
    const bool oky1 = (fy0 + 1.0f >= 0.0f) && (fy0 + 1.0f <= 127.0f);
    const int x0 = min(max((int)fx0, 0), HMW - 1);
    const int x1 = min(max((int)fx0 + 1, 0), HMW - 1);
    const int y0 = min(max((int)fy0, 0), HMH - 1);
    const int y1 = min(max((int)fy0 + 1, 0), HMH - 1);
    const float w00 = (okx0 && oky0) ? (1.0f - wxf) * (1.0f - wyf) : 0.0f;
    const float w01 = (okx1 && oky0) ? wxf * (1.0f - wyf) : 0.0f;
    const float w10 = (okx0 && oky1) ? (1.0f - wxf) * wyf : 0.0f;
    const float w11 = (okx1 && oky1) ? wxf * wyf : 0.0f;

    // ---- max weight over bboxes (gaussian depth mask) ----
    float maxw = 0.0f;
    if (bound) {
        const float dn = dnf[b];
        for (int m = 0; m < MM; ++m) {
            const float d = dep[b * MM + m];
            const float* bx = bbox + ((size_t)b * MM + m) * 4;
            const bool inb = (xhm >= bx[0]) && (yhm >= bx[1]) &&
                             (xhm <= bx[2]) && (yhm <= bx[3]);
            const float dz = zc - d * dn;
            const float w = __expf(dz * dz * (-1.0f / (2.0f * 200.0f * 200.0f)));
            if (inb && d >= 0.0f) maxw = fmaxf(maxw, w);
        }
    }

    // ---- per-joint bilinear sample & write ----
    const size_t outbase = (size_t)b * JJ * NB + (size_t)n;
    if (maxw > 0.0f) {
        const float* img = hm + (size_t)b * JJ * HMH * HMW;
        const int o00 = y0 * HMW + x0;
        const int o01 = y0 * HMW + x1;
        const int o10 = y1 * HMW + x0;
        const int o11 = y1 * HMW + x1;
        for (int j = 0; j < JJ; ++j) {
            const float* p = img + (size_t)j * HMH * HMW;
            const float s = p[o00] * w00 + p[o01] * w01 +
                            p[o10] * w10 + p[o11] * w11;
            float v = s * maxw;
            v = fminf(fmaxf(v, 0.0f), 1.0f);
            out[outbase + (size_t)j * NB] = v;
        }
    } else {
        for (int j = 0; j < JJ; ++j)
            out[outbase + (size_t)j * NB] = 0.0f;
    }

    // ---- grids output ----
    float* gout = out + (size_t)BB * JJ * NB + ((size_t)b * NB + n) * 3;
    gout[0] = gx;
    gout[1] = gy;
    gout[2] = gz;
}

extern "C" void kernel_launch(void* const* d_in, const int* in_sizes, int n_in,
                              void* d_out, int out_size, void* d_ws, size_t ws_size,
                              hipStream_t stream) {
    const float* hm     = (const float*)d_in[0];
    const float* gc     = (const float*)d_in[1];
    const float* center = (const float*)d_in[2];
    const float* scale  = (const float*)d_in[3];
    const float* R      = (const float*)d_in[4];
    const float* T      = (const float*)d_in[5];
    const float* f      = (const float*)d_in[6];
    const float* c      = (const float*)d_in[7];
    const float* k      = (const float*)d_in[8];
    const float* p      = (const float*)d_in[9];
    const float* bbox   = (const float*)d_in[10];
    const float* dep    = (const float*)d_in[11];
    const float* dnf    = (const float*)d_in[12];
    float* out = (float*)d_out;

    const int blocksPerB = NB / 256;          // 500
    dim3 grid(BB * blocksPerB);               // 8000 blocks
    dim3 block(256);
    project_kernel<<<grid, block, 0, stream>>>(hm, gc, center, scale, R, T, f, c,
                                               k, p, bbox, dep, dnf, out);
}